// Round 1
// baseline (68.434 us; speedup 1.0000x reference)
//
#include <hip/hip_runtime.h>

// Problem constants (from reference setup_inputs): P=128 polygons, N=128 pred
// points per polygon, M=1024 gt points per polygon, 3 levels, weights/3.
#define NPOLY 128
#define NPTS  128
#define NGT   1024

__global__ void zero_out_kernel(float* out) { out[0] = 0.0f; }

// One block per (level, polygon). 512 threads = 128 points x 4 gt-slices.
__global__ __launch_bounds__(512) void chamfer_loss_kernel(
    const float* __restrict__ pred0,
    const float* __restrict__ pred1,
    const float* __restrict__ pred2,
    const float* __restrict__ gt,
    float* __restrict__ out) {
    // gt pairs: each float4 holds two gt points (x0,y0,x1,y1). 8 KiB.
    __shared__ float4 gts[NGT / 2];
    __shared__ float wave_sums[8];

    const int b     = blockIdx.x;
    const int level = b >> 7;      // 0..2
    const int poly  = b & 127;

    const float* pred = (level == 0) ? pred0 : ((level == 1) ? pred1 : pred2);
    const float  w    = (level == 0) ? 0.2f : ((level == 1) ? 0.3f : 0.5f);

    const int t = threadIdx.x;

    // Stage this polygon's gt points into LDS: 512 float4 loads, coalesced.
    const float4* gsrc = (const float4*)(gt + (size_t)poly * (NGT * 2));
    gts[t] = gsrc[t];

    const int n = t >> 2;   // pred point index 0..127
    const int s = t & 3;    // gt slice 0..3

    // pred layout [1, P, N, 3]; keep coords 1:3
    const float* pp = pred + ((size_t)poly * NPTS + n) * 3 + 1;
    const float px = pp[0];
    const float py = pp[1];

    __syncthreads();

    // Min squared distance over this thread's 256 gt points (interleaved
    // pair index 4j+s -> 4 distinct broadcast addresses per wave, no bank
    // conflicts). Two accumulators for ILP.
    float dmin0 = 1e30f, dmin1 = 1e30f;
#pragma unroll 8
    for (int j = 0; j < NGT / 8; ++j) {
        float4 g = gts[(j << 2) + s];
        float dx0 = px - g.x, dy0 = py - g.y;
        float d20 = fmaf(dx0, dx0, dy0 * dy0);
        dmin0 = fminf(dmin0, d20);
        float dx1 = px - g.z, dy1 = py - g.w;
        float d21 = fmaf(dx1, dx1, dy1 * dy1);
        dmin1 = fminf(dmin1, d21);
    }
    float dmin = fminf(dmin0, dmin1);

    // Min across the 4 slices of this point (lanes 4n..4n+3 within a wave).
    dmin = fminf(dmin, __shfl_xor(dmin, 1));
    dmin = fminf(dmin, __shfl_xor(dmin, 2));

    // sqrt after min — monotone, identical selection to reference.
    float d = sqrtf(dmin);

    // Sum the 16 distinct points of this wave. Offsets 4..32 keep the s-coset,
    // so every lane ends with the same per-wave sum (each quad holds equal d).
    d += __shfl_xor(d, 4);
    d += __shfl_xor(d, 8);
    d += __shfl_xor(d, 16);
    d += __shfl_xor(d, 32);

    if ((t & 63) == 0) wave_sums[t >> 6] = d;
    __syncthreads();

    if (t == 0) {
        float total = 0.0f;
#pragma unroll
        for (int i = 0; i < 8; ++i) total += wave_sums[i];
        // loss += (w/3) * mean over P*N points
        atomicAdd(out, total * (w * (1.0f / (3.0f * NPOLY * NPTS))));
    }
}

extern "C" void kernel_launch(void* const* d_in, const int* in_sizes, int n_in,
                              void* d_out, int out_size, void* d_ws, size_t ws_size,
                              hipStream_t stream) {
    const float* pred0 = (const float*)d_in[0];
    const float* pred1 = (const float*)d_in[1];
    const float* pred2 = (const float*)d_in[2];
    const float* gt    = (const float*)d_in[3];
    float* out = (float*)d_out;

    zero_out_kernel<<<1, 1, 0, stream>>>(out);
    chamfer_loss_kernel<<<3 * NPOLY, 512, 0, stream>>>(pred0, pred1, pred2, gt, out);
}